// Round 6
// baseline (827.575 us; speedup 1.0000x reference)
//
#include <hip/hip_runtime.h>
#include <hip/hip_bf16.h>

#define B 16
#define C 512
#define W 4096
#define HEADS 8
#define HD 64
#define GROUPS 32
#define HIDDEN 512
#define OUT3 1536
#define CPG 16
#define GSIZE (CPG * W)
#define EPS 1e-5f

using bf16 = __hip_bfloat16;
typedef __attribute__((ext_vector_type(8))) short short8;
typedef __attribute__((ext_vector_type(4))) float f32x4;

__device__ __forceinline__ float bf_lo(unsigned u) { return __uint_as_float(u << 16); }
__device__ __forceinline__ float bf_hi(unsigned u) { return __uint_as_float(u & 0xffff0000u); }
__device__ __forceinline__ float bf2f(unsigned short s) { return __uint_as_float(((unsigned)s) << 16); }
__device__ __forceinline__ unsigned short f2bf(float f) {
    unsigned u = __float_as_uint(f);
    unsigned r = 0x7fffu + ((u >> 16) & 1u);
    return (unsigned short)((u + r) >> 16);
}
__device__ __forceinline__ unsigned pack2(float a, float b) {
    return (unsigned)f2bf(a) | ((unsigned)f2bf(b) << 16);
}

// ---------------- K1: GroupNorm stats (mean, rstd) per (b, group) ----------------
__global__ __launch_bounds__(256) void gn_stats_kernel(const float* __restrict__ x,
                                                       float2* __restrict__ stats) {
    __shared__ float s1[256], s2[256];
    int bg = blockIdx.x;
    const float4* p4 = (const float4*)(x + (size_t)bg * GSIZE);
    float sum = 0.f, sq = 0.f;
    for (int i = threadIdx.x; i < GSIZE / 4; i += 256) {
        float4 u = p4[i];
        sum += u.x + u.y + u.z + u.w;
        sq += u.x * u.x + u.y * u.y + u.z * u.z + u.w * u.w;
    }
    s1[threadIdx.x] = sum; s2[threadIdx.x] = sq;
    __syncthreads();
    for (int st = 128; st > 0; st >>= 1) {
        if (threadIdx.x < st) {
            s1[threadIdx.x] += s1[threadIdx.x + st];
            s2[threadIdx.x] += s2[threadIdx.x + st];
        }
        __syncthreads();
    }
    if (threadIdx.x == 0) {
        float mean = s1[0] / (float)GSIZE;
        float var = s2[0] / (float)GSIZE - mean * mean;
        stats[bg] = make_float2(mean, rsqrtf(var + EPS));
    }
}

// ---------------- K2a: fp32 -> bf16 cast (weights) ----------------
__global__ __launch_bounds__(256) void convw_kernel(const float* __restrict__ s,
                                                    ushort* __restrict__ d, int n4) {
    int i = blockIdx.x * 256 + threadIdx.x;
    if (i >= n4) return;
    float4 v = ((const float4*)s)[i];
    ushort4 o; o.x = f2bf(v.x); o.y = f2bf(v.y); o.z = f2bf(v.z); o.w = f2bf(v.w);
    ((ushort4*)d)[i] = o;
}

// ---------------- K2c: zero fp32 buffer (float4 granular) ----------------
__global__ __launch_bounds__(256) void zero_kernel(float* __restrict__ p, int n4) {
    int i = blockIdx.x * 256 + threadIdx.x;
    if (i < n4) ((float4*)p)[i] = make_float4(0.f, 0.f, 0.f, 0.f);
}

// ---------------- K2b: fused GroupNorm + transpose + bf16: xnT[b][w][c] ----------------
__global__ __launch_bounds__(256) void conv_xnt_kernel(
    const float* __restrict__ x, const float* __restrict__ gnw, const float* __restrict__ gnb,
    const float2* __restrict__ stats, ushort* __restrict__ xnT) {
    __shared__ ushort tile[64][68];
    int b = blockIdx.z, c0 = blockIdx.y * 64, w0 = blockIdx.x * 64;
    int t = threadIdx.x;
    int rc = t >> 4, rw = (t & 15) * 4;
#pragma unroll
    for (int p = 0; p < 4; p++) {
        int cl = p * 16 + rc;
        int c = c0 + cl;
        float2 st = stats[b * GROUPS + (c >> 4)];
        float gw = gnw[c], gb = gnb[c];
        float scale = st.y * gw;
        float shift = gb - st.x * scale;
        float4 v = *(const float4*)(x + ((size_t)b * C + c) * W + w0 + rw);
        tile[cl][rw + 0] = f2bf(v.x * scale + shift);
        tile[cl][rw + 1] = f2bf(v.y * scale + shift);
        tile[cl][rw + 2] = f2bf(v.z * scale + shift);
        tile[cl][rw + 3] = f2bf(v.w * scale + shift);
    }
    __syncthreads();
#pragma unroll
    for (int p = 0; p < 4; p++) {
        int wl = p * 16 + rc;
        int cl = (t & 15) * 4;
        ushort4 o;
        o.x = tile[cl + 0][wl]; o.y = tile[cl + 1][wl];
        o.z = tile[cl + 2][wl]; o.w = tile[cl + 3][wl];
        *(ushort4*)(xnT + ((size_t)b * W + w0 + wl) * C + c0 + cl) = o;
    }
}

// ---------------- K3: register-direct MFMA GEMM (no LDS, no barriers) ----------------
// D[n][m] = sum_k A[m][k]*Bw[n][k] (+bias[n]). A: [Mx512] bf16 per-batch, Bw: [Nx512]
// (per-batch iff bBatch != 0). 512 threads = 8 waves (2m x 4n), per-wave 128x64 output,
// acc 128 VGPR. Fragments are loaded global->register (16B/lane; identical index math to
// the verified LDS path with Al -> Ab). Both operands are L2/LLC-hot at this K=512 shape
// (B re-read by 96 blocks; A's 6 n-tile readers land on one XCD: grid-linear dID=16==0 mod 8).
// No cross-wave interaction at all -> zero barriers, races impossible; compiler pipelines.
// For BF16_OUT (QKV): n0 < HIDDEN tiles are the q-part, written TRANSPOSED as qT[w][hd]
// (row stride HIDDEN) into the same q region; k/v tiles written [o][w] as before.
template <bool BF16_OUT>
__global__ __launch_bounds__(512, 2) void gemm_reg_kernel(
    const ushort* __restrict__ A, const ushort* __restrict__ Bw,
    const float* __restrict__ bias, void* __restrict__ Dv,
    long aBatch, long dBatch, long bBatch) {
    const int b = blockIdx.z;
    const int m0 = blockIdx.x * 256, n0 = blockIdx.y * 256;
    const int lane = threadIdx.x & 63, wid = threadIdx.x >> 6;
    const int wm = wid >> 2, wn = wid & 3;
    const int quad = lane >> 4, lr = lane & 15;

    // lane-fixed fragment base pointers (k-offset quad*8 folded in)
    const ushort* Arow = A + (size_t)b * aBatch + (size_t)(m0 + wm * 128 + lr) * 512 + quad * 8;
    const ushort* Brow = Bw + (size_t)b * bBatch + (size_t)(n0 + wn * 64 + lr) * 512 + quad * 8;

    f32x4 acc[8][4] = {};
#pragma unroll 2
    for (int kt = 0; kt < 8; kt++) {
        const int k0 = kt * 64;
        short8 af[8], bf[8];  // bf[j*2+ks]
#pragma unroll
        for (int j = 0; j < 4; j++) {
            bf[j * 2 + 0] = *(const short8*)(Brow + (size_t)(j * 16) * 512 + k0);
            bf[j * 2 + 1] = *(const short8*)(Brow + (size_t)(j * 16) * 512 + k0 + 32);
        }
#pragma unroll
        for (int i = 0; i < 8; i++)
            af[i] = *(const short8*)(Arow + (size_t)(i * 16) * 512 + k0);
#pragma unroll
        for (int i = 0; i < 8; i++) {
            acc[i][0] = __builtin_amdgcn_mfma_f32_16x16x32_bf16(af[i], bf[0], acc[i][0], 0, 0, 0);
            acc[i][1] = __builtin_amdgcn_mfma_f32_16x16x32_bf16(af[i], bf[2], acc[i][1], 0, 0, 0);
            acc[i][2] = __builtin_amdgcn_mfma_f32_16x16x32_bf16(af[i], bf[4], acc[i][2], 0, 0, 0);
            acc[i][3] = __builtin_amdgcn_mfma_f32_16x16x32_bf16(af[i], bf[6], acc[i][3], 0, 0, 0);
        }
#pragma unroll
        for (int i = 0; i < 8; i++)
            af[i] = *(const short8*)(Arow + (size_t)(i * 16) * 512 + k0 + 32);
#pragma unroll
        for (int i = 0; i < 8; i++) {
            acc[i][0] = __builtin_amdgcn_mfma_f32_16x16x32_bf16(af[i], bf[1], acc[i][0], 0, 0, 0);
            acc[i][1] = __builtin_amdgcn_mfma_f32_16x16x32_bf16(af[i], bf[3], acc[i][1], 0, 0, 0);
            acc[i][2] = __builtin_amdgcn_mfma_f32_16x16x32_bf16(af[i], bf[5], acc[i][2], 0, 0, 0);
            acc[i][3] = __builtin_amdgcn_mfma_f32_16x16x32_bf16(af[i], bf[7], acc[i][3], 0, 0, 0);
        }
    }

    // C/D layout: col(n) = lane&15, row(m) = quad*4 + reg.
    if constexpr (BF16_OUT) {
        ushort* Db = (ushort*)Dv + (size_t)b * dBatch;
        if (n0 < HIDDEN) {
            // q-part: transposed store qT[w = m][hd = n], row stride HIDDEN
#pragma unroll
            for (int i = 0; i < 8; i++) {
                int mb = m0 + wm * 128 + i * 16 + quad * 4;
#pragma unroll
                for (int j = 0; j < 4; j++) {
                    int n = n0 + wn * 64 + j * 16 + lr;
                    float bv = bias[n];
                    f32x4 v = acc[i][j];
#pragma unroll
                    for (int r = 0; r < 4; r++)
                        Db[(size_t)(mb + r) * HIDDEN + n] = f2bf(v[r] + bv);
                }
            }
        } else {
#pragma unroll
            for (int i = 0; i < 8; i++) {
                int mb = m0 + wm * 128 + i * 16 + quad * 4;
#pragma unroll
                for (int j = 0; j < 4; j++) {
                    int n = n0 + wn * 64 + j * 16 + lr;
                    float bv = bias[n];
                    f32x4 v = acc[i][j];
                    uint2 st;
                    st.x = pack2(v.x + bv, v.y + bv);
                    st.y = pack2(v.z + bv, v.w + bv);
                    *(uint2*)(Db + (size_t)n * W + mb) = st;
                }
            }
        }
    } else {
        float* Db = (float*)Dv + (size_t)b * dBatch;
#pragma unroll
        for (int i = 0; i < 8; i++) {
            int mb = m0 + wm * 128 + i * 16 + quad * 4;
#pragma unroll
            for (int j = 0; j < 4; j++) {
                int n = n0 + wn * 64 + j * 16 + lr;
                float bv = bias[n];
                f32x4 v = acc[i][j];
                float4 st = make_float4(v.x + bv, v.y + bv, v.z + bv, v.w + bv);
                *(float4*)(Db + (size_t)n * W + mb) = st;
            }
        }
    }
}

// ---------------- K4: MFMA kv-context, register-resident, 2-way n-split ------
// ctx[bh][d][e] += sum_{n in slice} exp(k[d,n]) * v[e,n];  sums[bh][d] += ...
// (max-subtraction dropped: k ~ N(0,1), exp(k) fp32-safe; softmax identical.)
// Grid (bh, slice=0..1): 256 blocks (full GPU). Wave wv covers n in
// [slice*2048 + wv*256, +256), 8 steps of 32. K,V fragments global->register,
// exp+bf16-pack in registers, 2-deep static double buffer (named reg sets).
// Per-block merge in LDS, then one global atomicAdd pass (ctx/sums pre-zeroed).
#define LOADKV(KR, VR, n0_)                                                                  \
    {                                                                                        \
        _Pragma("unroll") for (int i = 0; i < 4; i++) {                                      \
            KR[i] = *(const uint4*)(kbase + (size_t)(i * 16 + lr) * W + (n0_) + quad * 8);   \
            VR[i] = *(const uint4*)(vbase + (size_t)(i * 16 + lr) * W + (n0_) + quad * 8);   \
        }                                                                                    \
    }
#define STEPKV(KR, VR)                                                                       \
    {                                                                                        \
        short8 af[4], bfv[4];                                                                \
        _Pragma("unroll") for (int i = 0; i < 4; i++) {                                      \
            uint4 u = KR[i];                                                                 \
            float e0 = __expf(bf_lo(u.x)), e1 = __expf(bf_hi(u.x));                          \
            float e2 = __expf(bf_lo(u.y)), e3 = __expf(bf_hi(u.y));                          \
            float e4 = __expf(bf_lo(u.z)), e5 = __expf(bf_hi(u.z));                          \
            float e6 = __expf(bf_lo(u.w)), e7 = __expf(bf_hi(u.w));                          \
            psum[i] += e0 + e1 + e2 + e3 + e4 + e5 + e6 + e7;                                \
            uint4 pk;                                                                        \
            pk.x = pack2(e0, e1); pk.y = pack2(e2, e3);                                      \
            pk.z = pack2(e4, e5); pk.w = pack2(e6, e7);                                      \
            af[i] = *(short8*)&pk;                                                           \
            bfv[i] = *(short8*)&VR[i];                                                       \
        }                                                                                    \
        _Pragma("unroll") for (int i = 0; i < 4; i++)                                        \
            _Pragma("unroll") for (int j = 0; j < 4; j++)                                    \
                acc[i][j] = __builtin_amdgcn_mfma_f32_16x16x32_bf16(af[i], bfv[j],           \
                                                                    acc[i][j], 0, 0, 0);     \
    }

__global__ __launch_bounds__(512) void kv_ctx_kernel(const ushort* __restrict__ qkv,
                                                     float* __restrict__ ctx,
                                                     float* __restrict__ sums) {
    __shared__ float ctxS[64][68];
    __shared__ float ssum[64];
    int bh = blockIdx.x, slice = blockIdx.y;
    int b = bh >> 3, h = bh & 7;
    const ushort* kbase = qkv + ((size_t)b * OUT3 + HIDDEN + h * HD) * W;
    const ushort* vbase = qkv + ((size_t)b * OUT3 + 2 * HIDDEN + h * HD) * W;
    int t = threadIdx.x, lane = t & 63, wv = t >> 6;
    int quad = lane >> 4, lr = lane & 15;

    for (int i = t; i < 64 * 68; i += 512) ((float*)ctxS)[i] = 0.f;
    if (t < 64) ssum[t] = 0.f;
    __syncthreads();

    const int nbase = slice * 2048 + wv * 256;
    f32x4 acc[4][4] = {};
    float psum[4] = {0.f, 0.f, 0.f, 0.f};
    uint4 ka[4], va[4], kb[4], vb[4];

    LOADKV(ka, va, nbase);
    for (int s = 0; s < 8; s += 2) {
        if (s + 1 < 8) LOADKV(kb, vb, nbase + (s + 1) * 32);
        STEPKV(ka, va);
        if (s + 2 < 8) LOADKV(ka, va, nbase + (s + 2) * 32);
        STEPKV(kb, vb);
    }

    // merge into ctxS. D layout: row d = i*16+quad*4+reg, col e = j*16+lr.
#pragma unroll
    for (int i = 0; i < 4; i++)
#pragma unroll
        for (int j = 0; j < 4; j++) {
            f32x4 v = acc[i][j];
#pragma unroll
            for (int r = 0; r < 4; r++)
                atomicAdd(&ctxS[i * 16 + quad * 4 + r][j * 16 + lr], v[r]);
        }
#pragma unroll
    for (int i = 0; i < 4; i++) {
        float v = psum[i];
        v += __shfl_xor(v, 16);
        v += __shfl_xor(v, 32);
        if (quad == 0) atomicAdd(&ssum[i * 16 + lr], v);
    }
    __syncthreads();
    {
        int d = t >> 3, e0 = (t & 7) * 8;
        float* dst = ctx + (size_t)bh * 4096 + d * 64 + e0;
#pragma unroll
        for (int e = 0; e < 8; e++) atomicAdd(dst + e, ctxS[d][e0 + e]);
    }
    if (t < 64) atomicAdd(&sums[(size_t)bh * 64 + t], ssum[t]);
}

// ---------------- K5: Weff[b][c][h*64+d] = (1/sums[b,h,d]) * sum_e wo[c][h*64+e]*ctx[b,h,d,e]
__global__ __launch_bounds__(256) void weff_kernel(const float* __restrict__ wo,
                                                   const float* __restrict__ ctx,
                                                   const float* __restrict__ sums,
                                                   ushort* __restrict__ weff) {
    __shared__ ushort woS[128 * 64];  // 16 KiB bf16 [c-local][e]
    __shared__ float ctxS[64][65];
    int cz = blockIdx.x, h = blockIdx.y, b = blockIdx.z;
    int bh = b * 8 + h;
    int t = threadIdx.x;
    for (int f = t; f < 1024; f += 256) {
        int d = f >> 4, c4 = (f & 15) * 4;
        float4 v = *(const float4*)(ctx + (size_t)bh * 4096 + d * 64 + c4);
        ctxS[d][c4 + 0] = v.x; ctxS[d][c4 + 1] = v.y;
        ctxS[d][c4 + 2] = v.z; ctxS[d][c4 + 3] = v.w;
    }
    for (int f = t; f < 1024; f += 256) {
        int cl = f >> 3, e8 = (f & 7) * 8;
        const float4* p = (const float4*)(wo + (size_t)(cz * 128 + cl) * HIDDEN + h * 64 + e8);
        float4 a = p[0], c = p[1];
        uint4 pk;
        pk.x = pack2(a.x, a.y); pk.y = pack2(a.z, a.w);
        pk.z = pack2(c.x, c.y); pk.w = pack2(c.z, c.w);
        *(uint4*)&woS[cl * 64 + e8] = pk;
    }
    __syncthreads();
    int d = t & 63, wvq = t >> 6;
    float pd = 1.0f / sums[(size_t)bh * 64 + d];
    for (int i = 0; i < 32; i++) {
        int cl = wvq * 32 + i;
        float acc = 0.f;
#pragma unroll
        for (int e = 0; e < 64; e++)
            acc += bf2f(woS[cl * 64 + e]) * ctxS[d][e];
        int c = cz * 128 + cl;
        weff[(size_t)b * (HIDDEN * HIDDEN) + (size_t)c * HIDDEN + h * 64 + d] = f2bf(acc * pd);
    }
}

extern "C" void kernel_launch(void* const* d_in, const int* in_sizes, int n_in,
                              void* d_out, int out_size, void* d_ws, size_t ws_size,
                              hipStream_t stream) {
    const float* x   = (const float*)d_in[0];
    const float* gnw = (const float*)d_in[1];
    const float* gnb = (const float*)d_in[2];
    const float* wq  = (const float*)d_in[3];
    const float* bq  = (const float*)d_in[4];
    const float* wo  = (const float*)d_in[5];
    const float* bo  = (const float*)d_in[6];
    float* out = (float*)d_out;

    char* ws = (char*)d_ws;
    // Lifetime-aliased layout (<= 258 MiB proven footprint):
    ushort* qkv   = (ushort*)ws;                    // [0,192Mi) qkv[b][o][w]; q-part stored as qT[b][w][512]
    ushort* xnT   = (ushort*)(ws + 201326592ull);   // [192Mi,256Mi) xnT (dead after QKV gemm)
    ushort* weff  = xnT;                            //   Weff[b][512][512] bf16 (8 MiB), written post-gemm
    float*  sums  = (float*)(ws + 209715200ull);    //   [200Mi, +32KiB) row sums (post-gemm)
    ushort* wqb   = (ushort*)(ws + 268435456ull);   // [256Mi) wqb (dead after QKV gemm)
    float*  ctx   = (float*)(ws + 268435456ull);    //   ctx 2 MiB (written post-gemm)
    float2* stats = (float2*)(ws + 270532608ull);   // 4 KiB (dead after conv_xnt)

    gn_stats_kernel<<<B * GROUPS, 256, 0, stream>>>(x, stats);
    convw_kernel<<<(OUT3 * C / 4 + 255) / 256, 256, 0, stream>>>(wq, wqb, OUT3 * C / 4);
    conv_xnt_kernel<<<dim3(W / 64, C / 64, B), 256, 0, stream>>>(x, gnw, gnb, stats, xnT);
    gemm_reg_kernel<true><<<dim3(W / 256, OUT3 / 256, B), 512, 0, stream>>>(
        xnT, wqb, bq, qkv, (long)W * C, (long)OUT3 * W, 0L);
    zero_kernel<<<(524288 / 4 + 255) / 256, 256, 0, stream>>>(ctx, 524288 / 4);
    zero_kernel<<<(8192 / 4 + 255) / 256, 256, 0, stream>>>(sums, 8192 / 4);
    kv_ctx_kernel<<<dim3(B * HEADS, 2), 512, 0, stream>>>(qkv, ctx, sums);
    weff_kernel<<<dim3(4, HEADS, B), 256, 0, stream>>>(wo, ctx, sums, weff);
    gemm_reg_kernel<false><<<dim3(W / 256, C / 256, B), 512, 0, stream>>>(
        qkv, weff, bo, out, (long)OUT3 * W, (long)C * W, (long)HIDDEN * HIDDEN);
}

// Round 8
// 596.499 us; speedup vs baseline: 1.3874x; 1.3874x over previous
//
#include <hip/hip_runtime.h>
#include <hip/hip_bf16.h>

#define B 16
#define C 512
#define W 4096
#define HEADS 8
#define HD 64
#define GROUPS 32
#define HIDDEN 512
#define OUT3 1536
#define CPG 16
#define GSIZE (CPG * W)
#define EPS 1e-5f

using bf16 = __hip_bfloat16;
typedef __attribute__((ext_vector_type(8))) short short8;
typedef __attribute__((ext_vector_type(4))) float f32x4;

__device__ __forceinline__ float bf_lo(unsigned u) { return __uint_as_float(u << 16); }
__device__ __forceinline__ float bf_hi(unsigned u) { return __uint_as_float(u & 0xffff0000u); }
__device__ __forceinline__ float bf2f(unsigned short s) { return __uint_as_float(((unsigned)s) << 16); }
__device__ __forceinline__ unsigned short f2bf(float f) {
    unsigned u = __float_as_uint(f);
    unsigned r = 0x7fffu + ((u >> 16) & 1u);
    return (unsigned short)((u + r) >> 16);
}
__device__ __forceinline__ unsigned pack2(float a, float b) {
    return (unsigned)f2bf(a) | ((unsigned)f2bf(b) << 16);
}

// async global->LDS, 16B per lane. LDS dest = wave-uniform base + lane*16.
__device__ __forceinline__ void async16(const ushort* g, ushort* l) {
    __builtin_amdgcn_global_load_lds((const __attribute__((address_space(1))) void*)g,
                                     (__attribute__((address_space(3))) void*)l, 16, 0, 0);
}

#define SBAR                                  \
    do {                                      \
        asm volatile("" ::: "memory");        \
        __builtin_amdgcn_s_barrier();         \
        asm volatile("" ::: "memory");        \
    } while (0)

// ---------------- K1: GroupNorm stats (mean, rstd) per (b, group) ----------------
__global__ __launch_bounds__(256) void gn_stats_kernel(const float* __restrict__ x,
                                                       float2* __restrict__ stats) {
    __shared__ float s1[256], s2[256];
    int bg = blockIdx.x;
    const float4* p4 = (const float4*)(x + (size_t)bg * GSIZE);
    float sum = 0.f, sq = 0.f;
    for (int i = threadIdx.x; i < GSIZE / 4; i += 256) {
        float4 u = p4[i];
        sum += u.x + u.y + u.z + u.w;
        sq += u.x * u.x + u.y * u.y + u.z * u.z + u.w * u.w;
    }
    s1[threadIdx.x] = sum; s2[threadIdx.x] = sq;
    __syncthreads();
    for (int st = 128; st > 0; st >>= 1) {
        if (threadIdx.x < st) {
            s1[threadIdx.x] += s1[threadIdx.x + st];
            s2[threadIdx.x] += s2[threadIdx.x + st];
        }
        __syncthreads();
    }
    if (threadIdx.x == 0) {
        float mean = s1[0] / (float)GSIZE;
        float var = s2[0] / (float)GSIZE - mean * mean;
        stats[bg] = make_float2(mean, rsqrtf(var + EPS));
    }
}

// ---------------- K2a: fp32 -> bf16 cast (weights) ----------------
__global__ __launch_bounds__(256) void convw_kernel(const float* __restrict__ s,
                                                    ushort* __restrict__ d, int n4) {
    int i = blockIdx.x * 256 + threadIdx.x;
    if (i >= n4) return;
    float4 v = ((const float4*)s)[i];
    ushort4 o; o.x = f2bf(v.x); o.y = f2bf(v.y); o.z = f2bf(v.z); o.w = f2bf(v.w);
    ((ushort4*)d)[i] = o;
}

// ---------------- K2b: fused GroupNorm + transpose + bf16: xnT[b][w][c] ----------------
__global__ __launch_bounds__(256) void conv_xnt_kernel(
    const float* __restrict__ x, const float* __restrict__ gnw, const float* __restrict__ gnb,
    const float2* __restrict__ stats, ushort* __restrict__ xnT) {
    __shared__ ushort tile[64][68];
    int b = blockIdx.z, c0 = blockIdx.y * 64, w0 = blockIdx.x * 64;
    int t = threadIdx.x;
    int rc = t >> 4, rw = (t & 15) * 4;
#pragma unroll
    for (int p = 0; p < 4; p++) {
        int cl = p * 16 + rc;
        int c = c0 + cl;
        float2 st = stats[b * GROUPS + (c >> 4)];
        float gw = gnw[c], gb = gnb[c];
        float scale = st.y * gw;
        float shift = gb - st.x * scale;
        float4 v = *(const float4*)(x + ((size_t)b * C + c) * W + w0 + rw);
        tile[cl][rw + 0] = f2bf(v.x * scale + shift);
        tile[cl][rw + 1] = f2bf(v.y * scale + shift);
        tile[cl][rw + 2] = f2bf(v.z * scale + shift);
        tile[cl][rw + 3] = f2bf(v.w * scale + shift);
    }
    __syncthreads();
#pragma unroll
    for (int p = 0; p < 4; p++) {
        int wl = p * 16 + rc;
        int cl = (t & 15) * 4;
        ushort4 o;
        o.x = tile[cl + 0][wl]; o.y = tile[cl + 1][wl];
        o.z = tile[cl + 2][wl]; o.w = tile[cl + 3][wl];
        *(ushort4*)(xnT + ((size_t)b * W + w0 + wl) * C + c0 + cl) = o;
    }
}

// ---------------- K3: 256x256 deep-pipelined MFMA GEMM (R2/R5-verified schedule) --------
// D[n][m] = sum_k A[m][k]*Bw[n][k] (+bias[n]). A: [Mx512] bf16 per-batch, Bw: [Nx512]
// (per-batch iff bBatch != 0). 512 threads = 8 waves (2m x 4n), per-wave 128x64 output.
// For BF16_OUT (QKV): n0 < HIDDEN tiles are the q-part, written TRANSPOSED as qT[w][hd]
// (row stride HIDDEN) via an LDS round-trip for coalesced stores; k/v tiles written [o][w].
template <bool BF16_OUT>
__global__ __launch_bounds__(512, 2) void gemm256_kernel(
    const ushort* __restrict__ A, const ushort* __restrict__ Bw,
    const float* __restrict__ bias, void* __restrict__ Dv,
    long aBatch, long dBatch, long bBatch) {
    __shared__ ushort sm[65536];  // 128 KiB
    const int b = blockIdx.z;
    const int m0 = blockIdx.x * 256, n0 = blockIdx.y * 256;
    const ushort* Ab = A + (size_t)b * aBatch;
    const ushort* Bwb = Bw + (size_t)b * bBatch;
    const int t = threadIdx.x;
    const int lane = t & 63, wid = t >> 6;
    const int wm = wid >> 2, wn = wid & 3;
    const int quad = lane >> 4, lr = lane & 15;

    // stage 128-row half h of an operand K-slab into buffer bb
    auto STAGE = [&](const ushort* P, int row0, int kt, int bb, int isB, int h) {
#pragma unroll
        for (int l = 0; l < 2; l++) {
            int f = t + 512 * l;
            int r = f & 127, kq = f >> 7;
            async16(P + (size_t)(row0 + h * 128 + r) * 512 + kt * 64 + kq * 8,
                    &sm[bb * 32768 + isB * 16384 + h * 1024 + kq * 2048 + r * 8]);
        }
    };

    const int NT = 8;  // K=512, BK=64
    STAGE(Bwb, n0, 0, 0, 1, 0); STAGE(Bwb, n0, 0, 0, 1, 1);
    STAGE(Ab, m0, 0, 0, 0, 0); STAGE(Ab, m0, 0, 0, 0, 1);
    STAGE(Bwb, n0, 1, 1, 1, 0); STAGE(Bwb, n0, 1, 1, 1, 1);
    STAGE(Ab, m0, 1, 1, 0, 0);
    asm volatile("s_waitcnt vmcnt(6)" ::: "memory");
    SBAR;

    f32x4 acc[8][4] = {};
    for (int kt = 0; kt < NT; kt++) {
        const int bb = kt & 1;
        const ushort* Al = &sm[bb * 32768];
        const ushort* Bl = &sm[bb * 32768 + 16384];
        short8 af[8], bf[8];  // bf[j*2+s]
        // ---- P0: ds_read all 8 B frags + 8 A s0 frags; stage A-half1(t+1) ----
#pragma unroll
        for (int j = 0; j < 4; j++) {
            bf[j * 2 + 0] = *(const short8*)&Bl[((0 + quad) * 256 + wn * 64 + j * 16 + lr) * 8];
            bf[j * 2 + 1] = *(const short8*)&Bl[((4 + quad) * 256 + wn * 64 + j * 16 + lr) * 8];
        }
#pragma unroll
        for (int i = 0; i < 8; i++)
            af[i] = *(const short8*)&Al[((0 + quad) * 256 + wm * 128 + i * 16 + lr) * 8];
        if (kt + 1 < NT) STAGE(Ab, m0, kt + 1, bb ^ 1, 0, 1);
        SBAR;
        __builtin_amdgcn_s_setprio(1);
#pragma unroll
        for (int i = 0; i < 8; i++) {
            acc[i][0] = __builtin_amdgcn_mfma_f32_16x16x32_bf16(af[i], bf[0], acc[i][0], 0, 0, 0);
            acc[i][1] = __builtin_amdgcn_mfma_f32_16x16x32_bf16(af[i], bf[2], acc[i][1], 0, 0, 0);
        }
        __builtin_amdgcn_s_setprio(0);
        asm volatile("s_waitcnt lgkmcnt(0)" ::: "memory");
        SBAR;
        // ---- P1: stage B-half0(t+2); MFMA s0 x j23 ----
        if (kt + 2 < NT) STAGE(Bwb, n0, kt + 2, bb, 1, 0);
        SBAR;
        __builtin_amdgcn_s_setprio(1);
#pragma unroll
        for (int i = 0; i < 8; i++) {
            acc[i][2] = __builtin_amdgcn_mfma_f32_16x16x32_bf16(af[i], bf[4], acc[i][2], 0, 0, 0);
            acc[i][3] = __builtin_amdgcn_mfma_f32_16x16x32_bf16(af[i], bf[6], acc[i][3], 0, 0, 0);
        }
        __builtin_amdgcn_s_setprio(0);
        SBAR;
        // ---- P2: ds_read A s1 frags; stage B-half1(t+2); MFMA s1 x j01 ----
#pragma unroll
        for (int i = 0; i < 8; i++)
            af[i] = *(const short8*)&Al[((4 + quad) * 256 + wm * 128 + i * 16 + lr) * 8];
        if (kt + 2 < NT) STAGE(Bwb, n0, kt + 2, bb, 1, 1);
        SBAR;
        __builtin_amdgcn_s_setprio(1);
#pragma unroll
        for (int i = 0; i < 8; i++) {
            acc[i][0] = __builtin_amdgcn_mfma_f32_16x16x32_bf16(af[i], bf[1], acc[i][0], 0, 0, 0);
            acc[i][1] = __builtin_amdgcn_mfma_f32_16x16x32_bf16(af[i], bf[3], acc[i][1], 0, 0, 0);
        }
        __builtin_amdgcn_s_setprio(0);
        SBAR;
        // ---- P3: stage A-half0(t+2); MFMA s1 x j23; boundary counted wait + barrier ----
        if (kt + 2 < NT) STAGE(Ab, m0, kt + 2, bb, 0, 0);
        SBAR;
        __builtin_amdgcn_s_setprio(1);
#pragma unroll
        for (int i = 0; i < 8; i++) {
            acc[i][2] = __builtin_amdgcn_mfma_f32_16x16x32_bf16(af[i], bf[5], acc[i][2], 0, 0, 0);
            acc[i][3] = __builtin_amdgcn_mfma_f32_16x16x32_bf16(af[i], bf[7], acc[i][3], 0, 0, 0);
        }
        __builtin_amdgcn_s_setprio(0);
        if (kt + 2 < NT) {
            asm volatile("s_waitcnt vmcnt(6)" ::: "memory");
        } else {
            asm volatile("s_waitcnt vmcnt(0)" ::: "memory");
        }
        SBAR;
    }

    // C/D layout: col(n) = lane&15, row(m) = quad*4 + reg.
    if constexpr (BF16_OUT) {
        ushort* Db = (ushort*)Dv + (size_t)b * dBatch;
        if (n0 < HIDDEN) {
            // q-part: transposed store qT[w = m][hd = n] via LDS (coalesced 64B stores).
            // 4 chunks of 64 m-rows; chunk c is produced by the 4 waves with wm == c>>1,
            // frag rows i in [(c&1)*4, (c&1)*4+4). Chunk-local row = ii*16 + quad*4 + r,
            // col = wn*64 + j*16 + lr  (verified identical to the old scalar-store target).
#pragma unroll
            for (int c = 0; c < 4; c++) {
                SBAR;  // protect previous chunk's copy-out before overwrite
                if (wm == (c >> 1)) {
                    int ibase = (c & 1) * 4;
#pragma unroll
                    for (int ii = 0; ii < 4; ii++) {
#pragma unroll
                        for (int j = 0; j < 4; j++) {
                            int n = n0 + wn * 64 + j * 16 + lr;
                            float bv = bias[n];
                            f32x4 v = acc[ibase + ii][j];
                            int col = wn * 64 + j * 16 + lr;
#pragma unroll
                            for (int r = 0; r < 4; r++)
                                sm[(ii * 16 + quad * 4 + r) * 256 + col] = f2bf(v[r] + bv);
                        }
                    }
                }
                SBAR;
                // all 512 threads: copy 64 rows x 256 bf16 (32 KiB), 64B per thread
                {
                    int row = t >> 3, seg = (t & 7) * 32;
                    ushort* dst = Db + (size_t)(m0 + c * 64 + row) * HIDDEN + n0 + seg;
                    uint4 v0 = *(const uint4*)&sm[row * 256 + seg];
                    uint4 v1 = *(const uint4*)&sm[row * 256 + seg + 8];
                    uint4 v2 = *(const uint4*)&sm[row * 256 + seg + 16];
                    uint4 v3 = *(const uint4*)&sm[row * 256 + seg + 24];
                    *(uint4*)(dst + 0) = v0;
                    *(uint4*)(dst + 8) = v1;
                    *(uint4*)(dst + 16) = v2;
                    *(uint4*)(dst + 24) = v3;
                }
            }
        } else {
#pragma unroll
            for (int i = 0; i < 8; i++) {
                int mb = m0 + wm * 128 + i * 16 + quad * 4;
#pragma unroll
                for (int j = 0; j < 4; j++) {
                    int n = n0 + wn * 64 + j * 16 + lr;
                    float bv = bias[n];
                    f32x4 v = acc[i][j];
                    uint2 st;
                    st.x = pack2(v.x + bv, v.y + bv);
                    st.y = pack2(v.z + bv, v.w + bv);
                    *(uint2*)(Db + (size_t)n * W + mb) = st;
                }
            }
        }
    } else {
        float* Db = (float*)Dv + (size_t)b * dBatch;
#pragma unroll
        for (int i = 0; i < 8; i++) {
            int mb = m0 + wm * 128 + i * 16 + quad * 4;
#pragma unroll
            for (int j = 0; j < 4; j++) {
                int n = n0 + wn * 64 + j * 16 + lr;
                float bv = bias[n];
                f32x4 v = acc[i][j];
                float4 st = make_float4(v.x + bv, v.y + bv, v.z + bv, v.w + bv);
                *(float4*)(Db + (size_t)n * W + mb) = st;
            }
        }
    }
}

// ---------------- K4: MFMA kv-context, fully register-resident (R5-verified) ------
// ctx[bh][d][e] = sum_n exp(k[d,n]) * v[e,n];  sums[bh][d] = sum_n exp(k[d,n]).
// (max-subtraction dropped: k ~ N(0,1), exp fp32-safe; softmax identical.)
#define LOADKV(KR, VR, n0_)                                                                  \
    {                                                                                        \
        _Pragma("unroll") for (int i = 0; i < 4; i++) {                                      \
            KR[i] = *(const uint4*)(kbase + (size_t)(i * 16 + lr) * W + (n0_) + quad * 8);   \
            VR[i] = *(const uint4*)(vbase + (size_t)(i * 16 + lr) * W + (n0_) + quad * 8);   \
        }                                                                                    \
    }
#define STEPKV(KR, VR)                                                                       \
    {                                                                                        \
        short8 af[4], bfv[4];                                                                \
        _Pragma("unroll") for (int i = 0; i < 4; i++) {                                      \
            uint4 u = KR[i];                                                                 \
            float e0 = __expf(bf_lo(u.x)), e1 = __expf(bf_hi(u.x));                          \
            float e2 = __expf(bf_lo(u.y)), e3 = __expf(bf_hi(u.y));                          \
            float e4 = __expf(bf_lo(u.z)), e5 = __expf(bf_hi(u.z));                          \
            float e6 = __expf(bf_lo(u.w)), e7 = __expf(bf_hi(u.w));                          \
            psum[i] += e0 + e1 + e2 + e3 + e4 + e5 + e6 + e7;                                \
            uint4 pk;                                                                        \
            pk.x = pack2(e0, e1); pk.y = pack2(e2, e3);                                      \
            pk.z = pack2(e4, e5); pk.w = pack2(e6, e7);                                      \
            af[i] = *(short8*)&pk;                                                           \
            bfv[i] = *(short8*)&VR[i];                                                       \
        }                                                                                    \
        _Pragma("unroll") for (int i = 0; i < 4; i++)                                        \
            _Pragma("unroll") for (int j = 0; j < 4; j++)                                    \
                acc[i][j] = __builtin_amdgcn_mfma_f32_16x16x32_bf16(af[i], bfv[j],           \
                                                                    acc[i][j], 0, 0, 0);     \
    }

__global__ __launch_bounds__(512) void kv_ctx_kernel(const ushort* __restrict__ qkv,
                                                     float* __restrict__ ctx,
                                                     float* __restrict__ sums) {
    __shared__ float ctxS[64][68];
    __shared__ float ssum[64];
    int bh = blockIdx.x;
    int b = bh >> 3, h = bh & 7;
    const ushort* kbase = qkv + ((size_t)b * OUT3 + HIDDEN + h * HD) * W;
    const ushort* vbase = qkv + ((size_t)b * OUT3 + 2 * HIDDEN + h * HD) * W;
    int t = threadIdx.x, lane = t & 63, wv = t >> 6;
    int quad = lane >> 4, lr = lane & 15;

    for (int i = t; i < 64 * 68; i += 512) ((float*)ctxS)[i] = 0.f;
    if (t < 64) ssum[t] = 0.f;
    __syncthreads();

    const int nbase = wv * 512;
    f32x4 acc[4][4] = {};
    float psum[4] = {0.f, 0.f, 0.f, 0.f};
    uint4 ka[4], va[4], kb[4], vb[4];

    LOADKV(ka, va, nbase);
    for (int s = 0; s < 16; s += 2) {
        if (s + 1 < 16) LOADKV(kb, vb, nbase + (s + 1) * 32);
        STEPKV(ka, va);
        if (s + 2 < 16) LOADKV(ka, va, nbase + (s + 2) * 32);
        STEPKV(kb, vb);
    }

    // merge into ctxS (LDS float atomics). D layout: row d = i*16+quad*4+reg, col e = j*16+lr.
#pragma unroll
    for (int i = 0; i < 4; i++)
#pragma unroll
        for (int j = 0; j < 4; j++) {
            f32x4 v = acc[i][j];
#pragma unroll
            for (int r = 0; r < 4; r++)
                atomicAdd(&ctxS[i * 16 + quad * 4 + r][j * 16 + lr], v[r]);
        }
#pragma unroll
    for (int i = 0; i < 4; i++) {
        float v = psum[i];
        v += __shfl_xor(v, 16);
        v += __shfl_xor(v, 32);
        if (quad == 0) atomicAdd(&ssum[i * 16 + lr], v);
    }
    __syncthreads();
    {
        int d = t >> 3, e0 = (t & 7) * 8;
        float4 a = *(const float4*)&ctxS[d][e0];
        float4 c = *(const float4*)&ctxS[d][e0 + 4];
        float* dst = ctx + (size_t)bh * 4096 + d * 64 + e0;
        *(float4*)dst = a;
        *(float4*)(dst + 4) = c;
    }
    if (t < 64) sums[(size_t)bh * 64 + t] = ssum[t];
}

// ---------------- K5: Weff[b][c][h*64+d] = (1/sums[b,h,d]) * sum_e wo[c][h*64+e]*ctx[b,h,d,e]
__global__ __launch_bounds__(256) void weff_kernel(const float* __restrict__ wo,
                                                   const float* __restrict__ ctx,
                                                   const float* __restrict__ sums,
                                                   ushort* __restrict__ weff) {
    __shared__ ushort woS[128 * 64];  // 16 KiB bf16 [c-local][e]
    __shared__ float ctxS[64][65];
    int cz = blockIdx.x, h = blockIdx.y, b = blockIdx.z;
    int bh = b * 8 + h;
    int t = threadIdx.x;
    for (int f = t; f < 1024; f += 256) {
        int d = f >> 4, c4 = (f & 15) * 4;
        float4 v = *(const float4*)(ctx + (size_t)bh * 4096 + d * 64 + c4);
        ctxS[d][c4 + 0] = v.x; ctxS[d][c4 + 1] = v.y;
        ctxS[d][c4 + 2] = v.z; ctxS[d][c4 + 3] = v.w;
    }
    for (int f = t; f < 1024; f += 256) {
        int cl = f >> 3, e8 = (f & 7) * 8;
        const float4* p = (const float4*)(wo + (size_t)(cz * 128 + cl) * HIDDEN + h * 64 + e8);
        float4 a = p[0], c = p[1];
        uint4 pk;
        pk.x = pack2(a.x, a.y); pk.y = pack2(a.z, a.w);
        pk.z = pack2(c.x, c.y); pk.w = pack2(c.z, c.w);
        *(uint4*)&woS[cl * 64 + e8] = pk;
    }
    __syncthreads();
    int d = t & 63, wvq = t >> 6;
    float pd = 1.0f / sums[(size_t)bh * 64 + d];
    for (int i = 0; i < 32; i++) {
        int cl = wvq * 32 + i;
        float acc = 0.f;
#pragma unroll
        for (int e = 0; e < 64; e++)
            acc += bf2f(woS[cl * 64 + e]) * ctxS[d][e];
        int c = cz * 128 + cl;
        weff[(size_t)b * (HIDDEN * HIDDEN) + (size_t)c * HIDDEN + h * 64 + d] = f2bf(acc * pd);
    }
}

extern "C" void kernel_launch(void* const* d_in, const int* in_sizes, int n_in,
                              void* d_out, int out_size, void* d_ws, size_t ws_size,
                              hipStream_t stream) {
    const float* x   = (const float*)d_in[0];
    const float* gnw = (const float*)d_in[1];
    const float* gnb = (const float*)d_in[2];
    const float* wq  = (const float*)d_in[3];
    const float* bq  = (const float*)d_in[4];
    const float* wo  = (const float*)d_in[5];
    const float* bo  = (const float*)d_in[6];
    float* out = (float*)d_out;

    char* ws = (char*)d_ws;
    // Lifetime-aliased layout (<= 258 MiB proven footprint):
    ushort* qkv   = (ushort*)ws;                    // [0,192Mi) qkv[b][o][w]; q-part stored as qT[b][w][512]
    ushort* xnT   = (ushort*)(ws + 201326592ull);   // [192Mi,256Mi) xnT (dead after QKV gemm)
    ushort* weff  = xnT;                            //   Weff[b][512][512] bf16 (8 MiB), written post-gemm
    float*  sums  = (float*)(ws + 209715200ull);    //   [200Mi, +32KiB) row sums (post-gemm)
    ushort* wqb   = (ushort*)(ws + 268435456ull);   // [256Mi) wqb (dead after QKV gemm)
    float*  ctx   = (float*)(ws + 268435456ull);    //   ctx 2 MiB (written post-gemm)
    float2* stats = (float2*)(ws + 270532608ull);   // 4 KiB (dead after conv_xnt)

    gn_stats_kernel<<<B * GROUPS, 256, 0, stream>>>(x, stats);
    convw_kernel<<<(OUT3 * C / 4 + 255) / 256, 256, 0, stream>>>(wq, wqb, OUT3 * C / 4);
    conv_xnt_kernel<<<dim3(W / 64, C / 64, B), 256, 0, stream>>>(x, gnw, gnb, stats, xnT);
    gemm256_kernel<true><<<dim3(W / 256, OUT3 / 256, B), 512, 0, stream>>>(
        xnT, wqb, bq, qkv, (long)W * C, (long)OUT3 * W, 0L);
    kv_ctx_kernel<<<B * HEADS, 512, 0, stream>>>(qkv, ctx, sums);
    weff_kernel<<<dim3(4, HEADS, B), 256, 0, stream>>>(wo, ctx, sums, weff);
    gemm256_kernel<false><<<dim3(W / 256, C / 256, B), 512, 0, stream>>>(
        qkv, weff, bo, out, (long)OUT3 * W, (long)C * W, (long)HIDDEN * HIDDEN);
}